// Round 1
// baseline (89913.055 us; speedup 1.0000x reference)
//
#include <hip/hip_runtime.h>
#include <hip/hip_bf16.h>

#define B_   8
#define T_   2048
#define D_   1024
#define OUT1_OFF 8388608ull   // 8*2048*512

typedef unsigned short u16;
typedef unsigned int   u32;

__device__ __forceinline__ u16 f2bf(float f) {
  u32 u = __builtin_bit_cast(u32, f);
  u32 r = (u + 0x7fffu + ((u >> 16) & 1u)) >> 16;   // RNE
  return (u16)r;
}
__device__ __forceinline__ float bf2f(u16 s) {
  u32 u = ((u32)s) << 16;
  return __builtin_bit_cast(float, u);
}

// ---------------------------------------------------------------- init
__global__ void k_init(float* hbuf, u32* cnts) {
  int tid = threadIdx.x;
  for (int i = tid; i < 16384; i += 256) hbuf[i] = 0.f;   // both h parity buffers
  for (int i = tid; i < 1024; i += 256) cnts[i] = 0u;
}

// ---------------------------------------------------------------- weight prep
// WT  (bf16) [3072][1024]: WT[g*1024+j][k] = W_g[k][j]        (k < 1024, x-part)
// WhT (f32)  [3072][1024]: WhT[g*1024+j][k] = W_g[1024+k][j]  (h-part)
__global__ __launch_bounds__(256) void k_prep(const float* __restrict__ Wr,
                                              const float* __restrict__ Wu,
                                              const float* __restrict__ Wc,
                                              u16* __restrict__ WT,
                                              float* __restrict__ WhT) {
  __shared__ float tile[32][33];
  int bid = blockIdx.x;
  int g = bid >> 11;          // 0..2
  int rest = bid & 2047;
  int kt = rest >> 5;         // 0..63  (row tile over 2048)
  int jt = rest & 31;         // 0..31  (col tile over 1024)
  const float* W = (g == 0) ? Wr : ((g == 1) ? Wu : Wc);
  int tid = threadIdx.x;
  int r = tid >> 3, c4 = (tid & 7) * 4;
  const float4 v = *(const float4*)&W[(size_t)(kt * 32 + r) * 1024 + jt * 32 + c4];
  tile[r][c4 + 0] = v.x; tile[r][c4 + 1] = v.y;
  tile[r][c4 + 2] = v.z; tile[r][c4 + 3] = v.w;
  __syncthreads();
  int n = g * 1024 + jt * 32 + r;
  if (kt < 32) {
    int k = kt * 32 + c4;
    ushort4 o;
    o.x = f2bf(tile[c4 + 0][r]); o.y = f2bf(tile[c4 + 1][r]);
    o.z = f2bf(tile[c4 + 2][r]); o.w = f2bf(tile[c4 + 3][r]);
    *(ushort4*)&WT[(size_t)n * 1024 + k] = o;
  } else {
    int k = (kt - 32) * 32 + c4;
    float4 o;
    o.x = tile[c4 + 0][r]; o.y = tile[c4 + 1][r];
    o.z = tile[c4 + 2][r]; o.w = tile[c4 + 3][r];
    *(float4*)&WhT[(size_t)n * 1024 + k] = o;
  }
}

// ---------------------------------------------------------------- embedding gather -> bf16
__global__ __launch_bounds__(256) void k_gather(const int* __restrict__ tok,
                                                const float* __restrict__ er,
                                                const float* __restrict__ ei,
                                                u16* __restrict__ XS) {
  int row = blockIdx.x * 2 + (threadIdx.x >> 7);  // 0..16383 = b*T+t
  int lt = threadIdx.x & 127;
  int tk = tok[row];
  int c0 = lt * 8;
  const float* p = (c0 < 512) ? (er + (size_t)tk * 512 + c0)
                              : (ei + (size_t)tk * 512 + (c0 - 512));
  float4 v1 = *(const float4*)p;
  float4 v2 = *(const float4*)(p + 4);
  uint4 o;
  o.x = (u32)f2bf(v1.x) | ((u32)f2bf(v1.y) << 16);
  o.y = (u32)f2bf(v1.z) | ((u32)f2bf(v1.w) << 16);
  o.z = (u32)f2bf(v2.x) | ((u32)f2bf(v2.y) << 16);
  o.w = (u32)f2bf(v2.z) | ((u32)f2bf(v2.w) << 16);
  *(uint4*)&XS[(size_t)row * 1024 + c0] = o;
}

// ---------------------------------------------------------------- bf16 MFMA GEMM: XW = XS @ W_top
typedef __attribute__((ext_vector_type(8))) __bf16 bf16x8;
typedef __attribute__((ext_vector_type(4))) float f32x4;

__device__ __forceinline__ void gload16(const void* g, void* l) {
  __builtin_amdgcn_global_load_lds((const __attribute__((address_space(1))) void*)g,
                                   (__attribute__((address_space(3))) void*)l, 16, 0, 0);
}

__global__ __launch_bounds__(256) void k_gemm(const u16* __restrict__ XS,
                                              const u16* __restrict__ WT,
                                              u16* __restrict__ XW) {
  __shared__ u16 As[128 * 32];
  __shared__ u16 Bs[128 * 32];
  int bid = blockIdx.x;
  int m0 = (bid & 127) * 128;   // 128 m-tiles
  int n0 = (bid >> 7) * 128;    // 24 n-tiles
  int tid = threadIdx.x;
  int wave = tid >> 6, lane = tid & 63;
  int wm = wave >> 1, wn = wave & 1;
  f32x4 acc[4][4] = {};
  int lr = lane & 15, lk = (lane >> 4) * 8;
  int srow = lane >> 2, sc8 = (lane & 3) * 8;
  for (int k0 = 0; k0 < 1024; k0 += 32) {
#pragma unroll
    for (int q = 0; q < 2; ++q) {
      int rbase = wave * 32 + q * 16;
      gload16(XS + (size_t)(m0 + rbase + srow) * 1024 + k0 + sc8, &As[rbase * 32]);
      gload16(WT + (size_t)(n0 + rbase + srow) * 1024 + k0 + sc8, &Bs[rbase * 32]);
    }
    __syncthreads();
    bf16x8 a[4], b[4];
#pragma unroll
    for (int mi = 0; mi < 4; ++mi) a[mi] = *(const bf16x8*)&As[(wm * 64 + mi * 16 + lr) * 32 + lk];
#pragma unroll
    for (int ni = 0; ni < 4; ++ni) b[ni] = *(const bf16x8*)&Bs[(wn * 64 + ni * 16 + lr) * 32 + lk];
#pragma unroll
    for (int mi = 0; mi < 4; ++mi)
#pragma unroll
      for (int ni = 0; ni < 4; ++ni)
        acc[mi][ni] = __builtin_amdgcn_mfma_f32_16x16x32_bf16(a[mi], b[ni], acc[mi][ni], 0, 0, 0);
    __syncthreads();
  }
#pragma unroll
  for (int mi = 0; mi < 4; ++mi)
#pragma unroll
    for (int ni = 0; ni < 4; ++ni) {
      int col = n0 + wn * 64 + ni * 16 + lr;
#pragma unroll
      for (int r = 0; r < 4; ++r) {
        int row = m0 + wm * 64 + mi * 16 + (lane >> 4) * 4 + r;
        XW[(size_t)row * 3072 + col] = f2bf(acc[mi][ni][r]);
      }
    }
}

// ---------------------------------------------------------------- persistent GRU
#define WPAD 1028

__device__ __forceinline__ float butterfly_reduce(float (&p)[64], int lane) {
#pragma unroll
  for (int s = 0; s < 6; ++s) {
    const int m = 1 << s;
    const int bit = (lane >> s) & 1;
#pragma unroll
    for (int i = 0; i < (64 >> (s + 1)); ++i) {
      float lo = p[2 * i], hi = p[2 * i + 1];
      float mine = bit ? hi : lo;
      float send = bit ? lo : hi;
      float recv = __shfl_xor(send, m, 64);
      p[i] = mine + recv;
    }
  }
  return p[0];
}

__global__ __launch_bounds__(256, 1) void k_gru(const float* __restrict__ WhT,
                                                const float* __restrict__ br,
                                                const float* __restrict__ bu,
                                                const float* __restrict__ bc,
                                                const u16* __restrict__ XW,
                                                float* hbuf, float* rhbuf,
                                                u32* cnts, float* out) {
  __shared__ float Wl[12][WPAD];   // rows 0-3: Wr cols, 4-7: Wu, 8-11: Wc
  __shared__ float part[4][64];
  __shared__ float u_l[4][8];
  __shared__ float hold[4][8];

  const int wg = blockIdx.x;
  const int tid = threadIdx.x;
  const int lane = tid & 63;
  const int wave = tid >> 6;
  const int j0 = wg * 4;
  const int slot = wg & 7;
  const int k4 = tid * 4;

  for (int i = tid; i < 12 * 1024; i += 256) {
    int c = i >> 10, k = i & 1023;
    int g = c >> 2, jj = c & 3;
    Wl[c][k] = WhT[(size_t)(g * 1024 + j0 + jj) * 1024 + k];
  }

  float biasA = 0.f;
  if (tid < 64) {
    int wA = tid >> 3, gA = wA >> 2, jjA = wA & 3;
    biasA = (gA == 0) ? br[j0 + jjA] : bu[j0 + jjA];
  }
  float bcB = 0.f;
  if (tid < 32) bcB = bc[j0 + (tid >> 3)];

  __syncthreads();

  for (int t = 0; t < T_; ++t) {
    if (t > 0) {
      if (tid == 0) {
        u32 target = (u32)(8 * t);
        while (__hip_atomic_load(&cnts[17 * 32], __ATOMIC_ACQUIRE, __HIP_MEMORY_SCOPE_AGENT) < target) {}
        __threadfence();
      }
      __syncthreads();
    }
    const float* hprev = hbuf + ((t + 1) & 1) * 8192;

    // prefetch finalize-A operands (overlaps with MAC)
    float xwA = 0.f, hjA = 0.f;
    if (tid < 64) {
      int bA = tid & 7, wA = tid >> 3, gA = wA >> 2, jjA = wA & 3;
      xwA = bf2f(XW[((size_t)bA * T_ + t) * 3072 + gA * 1024 + (j0 + jjA)]);
      hjA = hprev[bA * 1024 + j0 + jjA];
    }

    // ---- phase A: r,u pre-activations (register-blocked 8x8 over 4-k chunk)
    float4 hv[8], wv[8];
#pragma unroll
    for (int b = 0; b < 8; ++b) hv[b] = *(const float4*)&hprev[b * 1024 + k4];
#pragma unroll
    for (int w = 0; w < 8; ++w) wv[w] = *(const float4*)&Wl[w][k4];
    float acc[64];
#pragma unroll
    for (int w = 0; w < 8; ++w)
#pragma unroll
      for (int b = 0; b < 8; ++b)
        acc[w * 8 + b] = hv[b].x * wv[w].x + hv[b].y * wv[w].y +
                         hv[b].z * wv[w].z + hv[b].w * wv[w].w;
    float pa = butterfly_reduce(acc, lane);
    part[wave][lane] = pa;
    __syncthreads();

    if (tid < 64) {
      float dot = part[0][tid] + part[1][tid] + part[2][tid] + part[3][tid];
      float pre = dot + xwA + biasA;
      float sg = 1.f / (1.f + __expf(-pre));
      int bA = tid & 7, wA = tid >> 3, gA = wA >> 2, jjA = wA & 3;
      if (gA == 0) {
        rhbuf[bA * 1024 + j0 + jjA] = sg * hjA;
      } else {
        u_l[jjA][bA] = sg;
        hold[jjA][bA] = hjA;
      }
    }
    __syncthreads();
    if (tid == 0) {
      __threadfence();
      u32 prev = __hip_atomic_fetch_add(&cnts[slot * 32], 1u, __ATOMIC_ACQ_REL, __HIP_MEMORY_SCOPE_AGENT);
      if (((prev + 1) & 31) == 0)
        __hip_atomic_fetch_add(&cnts[8 * 32], 1u, __ATOMIC_RELEASE, __HIP_MEMORY_SCOPE_AGENT);
      u32 target = (u32)(8 * (t + 1));
      while (__hip_atomic_load(&cnts[8 * 32], __ATOMIC_ACQUIRE, __HIP_MEMORY_SCOPE_AGENT) < target) {}
      __threadfence();
    }
    __syncthreads();

    // ---- phase B: c, h_new
    float xwB = 0.f;
    if (tid < 32) {
      xwB = bf2f(XW[((size_t)(tid & 7) * T_ + t) * 3072 + 2048 + j0 + (tid >> 3)]);
    }
    float4 rv[8], wc4[4];
#pragma unroll
    for (int b = 0; b < 8; ++b) rv[b] = *(const float4*)&rhbuf[b * 1024 + k4];
#pragma unroll
    for (int c = 0; c < 4; ++c) wc4[c] = *(const float4*)&Wl[8 + c][k4];
#pragma unroll
    for (int w = 0; w < 8; ++w)
#pragma unroll
      for (int b = 0; b < 8; ++b) {
        float4 w2 = wc4[w & 3];
        acc[w * 8 + b] = rv[b].x * w2.x + rv[b].y * w2.y +
                         rv[b].z * w2.z + rv[b].w * w2.w;
      }
    float pb = butterfly_reduce(acc, lane);
    part[wave][lane] = pb;
    __syncthreads();
    if (tid < 32) {
      float dot = part[0][tid] + part[1][tid] + part[2][tid] + part[3][tid];
      float pre = dot + xwB + bcB;
      float ax = fabsf(pre);
      float e = __expf(-2.f * ax);
      float cv = copysignf((1.f - e) / (1.f + e), pre);
      int bB = tid & 7, jjB = tid >> 3;
      float uu = u_l[jjB][bB];
      float hn = (1.f - uu) * hold[jjB][bB] + uu * cv;
      int j = j0 + jjB;
      hbuf[(t & 1) * 8192 + bB * 1024 + j] = hn;
      size_t orow = (size_t)bB * T_ + t;
      if (j < 512) out[orow * 512 + j] = hn;
      else out[OUT1_OFF + orow * 512 + (j - 512)] = hn;
    }
    __syncthreads();
    if (tid == 0) {
      __threadfence();
      u32 prev = __hip_atomic_fetch_add(&cnts[(9 + slot) * 32], 1u, __ATOMIC_ACQ_REL, __HIP_MEMORY_SCOPE_AGENT);
      if (((prev + 1) & 31) == 0)
        __hip_atomic_fetch_add(&cnts[17 * 32], 1u, __ATOMIC_RELEASE, __HIP_MEMORY_SCOPE_AGENT);
    }
  }
}

// ---------------------------------------------------------------- in-place LayerNorm
__global__ __launch_bounds__(256) void k_ln(float* __restrict__ out,
                                            const float* __restrict__ sr,
                                            const float* __restrict__ brr,
                                            const float* __restrict__ si,
                                            const float* __restrict__ bii) {
  int row = blockIdx.x * 4 + (threadIdx.x >> 6);   // 0..32767
  int lane = threadIdx.x & 63;
  float* p = out + (size_t)row * 512;
  float4 v1 = ((const float4*)p)[lane];
  float4 v2 = ((const float4*)p)[64 + lane];
  float s1 = v1.x + v1.y + v1.z + v1.w + v2.x + v2.y + v2.z + v2.w;
  float s2 = v1.x * v1.x + v1.y * v1.y + v1.z * v1.z + v1.w * v1.w +
             v2.x * v2.x + v2.y * v2.y + v2.z * v2.z + v2.w * v2.w;
#pragma unroll
  for (int m = 1; m < 64; m <<= 1) { s1 += __shfl_xor(s1, m, 64); s2 += __shfl_xor(s2, m, 64); }
  float mean = s1 * (1.f / 512.f);
  float var = s2 * (1.f / 512.f) - mean * mean;
  float inv = rsqrtf(var + 1e-6f);
  bool hi2 = row >= 16384;
  const float* sc = hi2 ? si : sr;
  const float* bs = hi2 ? bii : brr;
  float4 g1 = ((const float4*)sc)[lane], g2 = ((const float4*)sc)[64 + lane];
  float4 b1 = ((const float4*)bs)[lane], b2 = ((const float4*)bs)[64 + lane];
  v1.x = (v1.x - mean) * inv * g1.x + b1.x;
  v1.y = (v1.y - mean) * inv * g1.y + b1.y;
  v1.z = (v1.z - mean) * inv * g1.z + b1.z;
  v1.w = (v1.w - mean) * inv * g1.w + b1.w;
  v2.x = (v2.x - mean) * inv * g2.x + b2.x;
  v2.y = (v2.y - mean) * inv * g2.y + b2.y;
  v2.z = (v2.z - mean) * inv * g2.z + b2.z;
  v2.w = (v2.w - mean) * inv * g2.w + b2.w;
  ((float4*)p)[lane] = v1;
  ((float4*)p)[64 + lane] = v2;
}

// ---------------------------------------------------------------- launch
extern "C" void kernel_launch(void* const* d_in, const int* in_sizes, int n_in,
                              void* d_out, int out_size, void* d_ws, size_t ws_size,
                              hipStream_t stream) {
  const int*   tok   = (const int*)d_in[0];
  const float* emb_r = (const float*)d_in[1];
  const float* emb_i = (const float*)d_in[2];
  const float* Wr    = (const float*)d_in[3];
  const float* br    = (const float*)d_in[4];
  const float* Wu    = (const float*)d_in[5];
  const float* bu    = (const float*)d_in[6];
  const float* Wc    = (const float*)d_in[7];
  const float* bc    = (const float*)d_in[8];
  const float* lnrs  = (const float*)d_in[9];
  const float* lnrb  = (const float*)d_in[10];
  const float* lnis  = (const float*)d_in[11];
  const float* lnib  = (const float*)d_in[12];
  float* out = (float*)d_out;
  char* ws = (char*)d_ws;

  u16*   XS    = (u16*)(ws);                       //  33,554,432 B
  u16*   WT    = (u16*)(ws + 33554432);            //   6,291,456 B
  u16*   XW    = (u16*)(ws + 39845888);            // 100,663,296 B
  float* WhT   = (float*)(ws + 140509184);         //  12,582,912 B
  float* hbuf  = (float*)(ws + 153092096);         //      65,536 B
  float* rhbuf = (float*)(ws + 153157632);         //      32,768 B
  u32*   cnts  = (u32*)(ws + 153190400);           //       4,096 B

  k_init<<<1, 256, 0, stream>>>(hbuf, cnts);
  k_prep<<<6144, 256, 0, stream>>>(Wr, Wu, Wc, WT, WhT);
  k_gather<<<8192, 256, 0, stream>>>(tok, emb_r, emb_i, XS);
  k_gemm<<<3072, 256, 0, stream>>>(XS, WT, XW);
  k_gru<<<256, 256, 0, stream>>>(WhT, br, bu, bc, XW, hbuf, rhbuf, cnts, out);
  k_ln<<<8192, 256, 0, stream>>>(out, lnrs, lnrb, lnis, lnib);
}

// Round 2
// 24545.761 us; speedup vs baseline: 3.6631x; 3.6631x over previous
//
#include <hip/hip_runtime.h>
#include <hip/hip_bf16.h>

#define B_   8
#define T_   2048
#define D_   1024
#define OUT1_OFF 8388608ull   // 8*2048*512

typedef unsigned short u16;
typedef unsigned int   u32;
typedef unsigned long long u64;

__device__ __forceinline__ u16 f2bf(float f) {
  u32 u = __builtin_bit_cast(u32, f);
  u32 r = (u + 0x7fffu + ((u >> 16) & 1u)) >> 16;   // RNE
  return (u16)r;
}
__device__ __forceinline__ float bf2f(u16 s) {
  u32 u = ((u32)s) << 16;
  return __builtin_bit_cast(float, u);
}

// device-coherent (sc0 sc1, memory-side) data exchange helpers
__device__ __forceinline__ float4 ld4cv(const float* p) {
  u64 a = __hip_atomic_load((const u64*)p,     __ATOMIC_RELAXED, __HIP_MEMORY_SCOPE_AGENT);
  u64 b = __hip_atomic_load((const u64*)p + 1, __ATOMIC_RELAXED, __HIP_MEMORY_SCOPE_AGENT);
  float4 v;
  v.x = __builtin_bit_cast(float, (u32)a); v.y = __builtin_bit_cast(float, (u32)(a >> 32));
  v.z = __builtin_bit_cast(float, (u32)b); v.w = __builtin_bit_cast(float, (u32)(b >> 32));
  return v;
}
__device__ __forceinline__ float ld1cv(const float* p) {
  u32 a = __hip_atomic_load((const u32*)p, __ATOMIC_RELAXED, __HIP_MEMORY_SCOPE_AGENT);
  return __builtin_bit_cast(float, a);
}
__device__ __forceinline__ void st1cv(float* p, float v) {
  __hip_atomic_store((u32*)p, __builtin_bit_cast(u32, v), __ATOMIC_RELAXED, __HIP_MEMORY_SCOPE_AGENT);
}

// ---------------------------------------------------------------- init
__global__ void k_init(float* hbuf, u32* cnts) {
  int tid = threadIdx.x;
  for (int i = tid; i < 16384; i += 256) hbuf[i] = 0.f;   // both h parity buffers
  for (int i = tid; i < 1024; i += 256) cnts[i] = 0u;
}

// ---------------------------------------------------------------- weight prep
__global__ __launch_bounds__(256) void k_prep(const float* __restrict__ Wr,
                                              const float* __restrict__ Wu,
                                              const float* __restrict__ Wc,
                                              u16* __restrict__ WT,
                                              float* __restrict__ WhT) {
  __shared__ float tile[32][33];
  int bid = blockIdx.x;
  int g = bid >> 11;          // 0..2
  int rest = bid & 2047;
  int kt = rest >> 5;         // 0..63  (row tile over 2048)
  int jt = rest & 31;         // 0..31  (col tile over 1024)
  const float* W = (g == 0) ? Wr : ((g == 1) ? Wu : Wc);
  int tid = threadIdx.x;
  int r = tid >> 3, c4 = (tid & 7) * 4;
  const float4 v = *(const float4*)&W[(size_t)(kt * 32 + r) * 1024 + jt * 32 + c4];
  tile[r][c4 + 0] = v.x; tile[r][c4 + 1] = v.y;
  tile[r][c4 + 2] = v.z; tile[r][c4 + 3] = v.w;
  __syncthreads();
  int n = g * 1024 + jt * 32 + r;
  if (kt < 32) {
    int k = kt * 32 + c4;
    ushort4 o;
    o.x = f2bf(tile[c4 + 0][r]); o.y = f2bf(tile[c4 + 1][r]);
    o.z = f2bf(tile[c4 + 2][r]); o.w = f2bf(tile[c4 + 3][r]);
    *(ushort4*)&WT[(size_t)n * 1024 + k] = o;
  } else {
    int k = (kt - 32) * 32 + c4;
    float4 o;
    o.x = tile[c4 + 0][r]; o.y = tile[c4 + 1][r];
    o.z = tile[c4 + 2][r]; o.w = tile[c4 + 3][r];
    *(float4*)&WhT[(size_t)n * 1024 + k] = o;
  }
}

// ---------------------------------------------------------------- embedding gather -> bf16
__global__ __launch_bounds__(256) void k_gather(const int* __restrict__ tok,
                                                const float* __restrict__ er,
                                                const float* __restrict__ ei,
                                                u16* __restrict__ XS) {
  int row = blockIdx.x * 2 + (threadIdx.x >> 7);  // 0..16383 = b*T+t
  int lt = threadIdx.x & 127;
  int tk = tok[row];
  int c0 = lt * 8;
  const float* p = (c0 < 512) ? (er + (size_t)tk * 512 + c0)
                              : (ei + (size_t)tk * 512 + (c0 - 512));
  float4 v1 = *(const float4*)p;
  float4 v2 = *(const float4*)(p + 4);
  uint4 o;
  o.x = (u32)f2bf(v1.x) | ((u32)f2bf(v1.y) << 16);
  o.y = (u32)f2bf(v1.z) | ((u32)f2bf(v1.w) << 16);
  o.z = (u32)f2bf(v2.x) | ((u32)f2bf(v2.y) << 16);
  o.w = (u32)f2bf(v2.z) | ((u32)f2bf(v2.w) << 16);
  *(uint4*)&XS[(size_t)row * 1024 + c0] = o;
}

// ---------------------------------------------------------------- bf16 MFMA GEMM: XW = XS @ W_top
typedef __attribute__((ext_vector_type(8))) __bf16 bf16x8;
typedef __attribute__((ext_vector_type(4))) float f32x4;

__device__ __forceinline__ void gload16(const void* g, void* l) {
  __builtin_amdgcn_global_load_lds((const __attribute__((address_space(1))) void*)g,
                                   (__attribute__((address_space(3))) void*)l, 16, 0, 0);
}

__global__ __launch_bounds__(256) void k_gemm(const u16* __restrict__ XS,
                                              const u16* __restrict__ WT,
                                              u16* __restrict__ XW) {
  __shared__ u16 As[128 * 32];
  __shared__ u16 Bs[128 * 32];
  int bid = blockIdx.x;
  int m0 = (bid & 127) * 128;   // 128 m-tiles
  int n0 = (bid >> 7) * 128;    // 24 n-tiles
  int tid = threadIdx.x;
  int wave = tid >> 6, lane = tid & 63;
  int wm = wave >> 1, wn = wave & 1;
  f32x4 acc[4][4] = {};
  int lr = lane & 15, lk = (lane >> 4) * 8;
  int srow = lane >> 2, sc8 = (lane & 3) * 8;
  for (int k0 = 0; k0 < 1024; k0 += 32) {
#pragma unroll
    for (int q = 0; q < 2; ++q) {
      int rbase = wave * 32 + q * 16;
      gload16(XS + (size_t)(m0 + rbase + srow) * 1024 + k0 + sc8, &As[rbase * 32]);
      gload16(WT + (size_t)(n0 + rbase + srow) * 1024 + k0 + sc8, &Bs[rbase * 32]);
    }
    __syncthreads();
    bf16x8 a[4], b[4];
#pragma unroll
    for (int mi = 0; mi < 4; ++mi) a[mi] = *(const bf16x8*)&As[(wm * 64 + mi * 16 + lr) * 32 + lk];
#pragma unroll
    for (int ni = 0; ni < 4; ++ni) b[ni] = *(const bf16x8*)&Bs[(wn * 64 + ni * 16 + lr) * 32 + lk];
#pragma unroll
    for (int mi = 0; mi < 4; ++mi)
#pragma unroll
      for (int ni = 0; ni < 4; ++ni)
        acc[mi][ni] = __builtin_amdgcn_mfma_f32_16x16x32_bf16(a[mi], b[ni], acc[mi][ni], 0, 0, 0);
    __syncthreads();
  }
#pragma unroll
  for (int mi = 0; mi < 4; ++mi)
#pragma unroll
    for (int ni = 0; ni < 4; ++ni) {
      int col = n0 + wn * 64 + ni * 16 + lr;
#pragma unroll
      for (int r = 0; r < 4; ++r) {
        int row = m0 + wm * 64 + mi * 16 + (lane >> 4) * 4 + r;
        XW[(size_t)row * 3072 + col] = f2bf(acc[mi][ni][r]);
      }
    }
}

// ---------------------------------------------------------------- persistent GRU
#define WPAD 1028

__device__ __forceinline__ float butterfly_reduce(float (&p)[64], int lane) {
#pragma unroll
  for (int s = 0; s < 6; ++s) {
    const int m = 1 << s;
    const int bit = (lane >> s) & 1;
#pragma unroll
    for (int i = 0; i < (64 >> (s + 1)); ++i) {
      float lo = p[2 * i], hi = p[2 * i + 1];
      float mine = bit ? hi : lo;
      float send = bit ? lo : hi;
      float recv = __shfl_xor(send, m, 64);
      p[i] = mine + recv;
    }
  }
  return p[0];
}

__global__ __launch_bounds__(256, 1) void k_gru(const float* __restrict__ WhT,
                                                const float* __restrict__ br,
                                                const float* __restrict__ bu,
                                                const float* __restrict__ bc,
                                                const u16* __restrict__ XW,
                                                float* hbuf, float* rhbuf,
                                                u32* cnts, float* out) {
  __shared__ float Wl[12][WPAD];   // rows 0-3: Wr cols, 4-7: Wu, 8-11: Wc
  __shared__ float part[4][64];
  __shared__ float u_l[4][8];
  __shared__ float hold[4][8];

  const int tid = threadIdx.x;
  const int lane = tid & 63;
  const int wave = tid >> 6;
  const int j0 = blockIdx.x * 4;
  const int k4 = tid * 4;
  u32* bar = cnts;   // single monotonic barrier counter

  for (int i = tid; i < 12 * 1024; i += 256) {
    int c = i >> 10, k = i & 1023;
    int g = c >> 2, jj = c & 3;
    Wl[c][k] = WhT[(size_t)(g * 1024 + j0 + jj) * 1024 + k];
  }

  float biasA = 0.f;
  if (tid < 64) {
    int wA = tid >> 3, gA = wA >> 2, jjA = wA & 3;
    biasA = (gA == 0) ? br[j0 + jjA] : bu[j0 + jjA];
  }
  float bcB = 0.f;
  if (tid < 32) bcB = bc[j0 + (tid >> 3)];

  __syncthreads();

  for (int t = 0; t < T_; ++t) {
    const float* hprev = hbuf + ((t + 1) & 1) * 8192;

    // prefetch finalize-A operands (overlaps with MAC)
    float xwA = 0.f, hjA = 0.f;
    if (tid < 64) {
      int bA = tid & 7, wA = tid >> 3, gA = wA >> 2, jjA = wA & 3;
      xwA = bf2f(XW[((size_t)bA * T_ + t) * 3072 + gA * 1024 + (j0 + jjA)]);
      hjA = ld1cv(&hprev[bA * 1024 + j0 + jjA]);
    }

    // ---- phase A: r,u pre-activations (register-blocked 8x8 over 4-k chunk)
    float4 hv[8], wv[8];
#pragma unroll
    for (int b = 0; b < 8; ++b) hv[b] = ld4cv(&hprev[b * 1024 + k4]);
#pragma unroll
    for (int w = 0; w < 8; ++w) wv[w] = *(const float4*)&Wl[w][k4];
    float acc[64];
#pragma unroll
    for (int w = 0; w < 8; ++w)
#pragma unroll
      for (int b = 0; b < 8; ++b)
        acc[w * 8 + b] = hv[b].x * wv[w].x + hv[b].y * wv[w].y +
                         hv[b].z * wv[w].z + hv[b].w * wv[w].w;
    float pa = butterfly_reduce(acc, lane);
    part[wave][lane] = pa;
    __syncthreads();

    if (tid < 64) {
      float dot = part[0][tid] + part[1][tid] + part[2][tid] + part[3][tid];
      float pre = dot + xwA + biasA;
      float sg = 1.f / (1.f + __expf(-pre));
      int bA = tid & 7, wA = tid >> 3, gA = wA >> 2, jjA = wA & 3;
      if (gA == 0) {
        st1cv(&rhbuf[bA * 1024 + j0 + jjA], sg * hjA);
      } else {
        u_l[jjA][bA] = sg;
        hold[jjA][bA] = hjA;
      }
    }
    __syncthreads();   // implicit vmcnt(0): rh write-through complete for all waves
    if (tid == 0) {
      u32 target = 256u * (u32)(2 * t + 1);
      __hip_atomic_fetch_add(bar, 1u, __ATOMIC_RELAXED, __HIP_MEMORY_SCOPE_AGENT);
      while (__hip_atomic_load(bar, __ATOMIC_RELAXED, __HIP_MEMORY_SCOPE_AGENT) < target) {}
    }
    __syncthreads();

    // ---- phase B: c, h_new
    float xwB = 0.f;
    if (tid < 32) {
      xwB = bf2f(XW[((size_t)(tid & 7) * T_ + t) * 3072 + 2048 + j0 + (tid >> 3)]);
    }
    float4 rv[8], wc4[4];
#pragma unroll
    for (int b = 0; b < 8; ++b) rv[b] = ld4cv(&rhbuf[b * 1024 + k4]);
#pragma unroll
    for (int c = 0; c < 4; ++c) wc4[c] = *(const float4*)&Wl[8 + c][k4];
#pragma unroll
    for (int w = 0; w < 8; ++w)
#pragma unroll
      for (int b = 0; b < 8; ++b) {
        float4 w2 = wc4[w & 3];
        acc[w * 8 + b] = rv[b].x * w2.x + rv[b].y * w2.y +
                         rv[b].z * w2.z + rv[b].w * w2.w;
      }
    float pb = butterfly_reduce(acc, lane);
    part[wave][lane] = pb;
    __syncthreads();
    if (tid < 32) {
      float dot = part[0][tid] + part[1][tid] + part[2][tid] + part[3][tid];
      float pre = dot + xwB + bcB;
      float ax = fabsf(pre);
      float e = __expf(-2.f * ax);
      float cv = copysignf((1.f - e) / (1.f + e), pre);
      int bB = tid & 7, jjB = tid >> 3;
      float uu = u_l[jjB][bB];
      float hn = (1.f - uu) * hold[jjB][bB] + uu * cv;
      int j = j0 + jjB;
      st1cv(&hbuf[(t & 1) * 8192 + bB * 1024 + j], hn);
      size_t orow = (size_t)bB * T_ + t;
      if (j < 512) out[orow * 512 + j] = hn;
      else out[OUT1_OFF + orow * 512 + (j - 512)] = hn;
    }
    __syncthreads();   // implicit vmcnt(0): h write-through complete for all waves
    if (t < T_ - 1) {
      if (tid == 0) {
        u32 target = 256u * (u32)(2 * t + 2);
        __hip_atomic_fetch_add(bar, 1u, __ATOMIC_RELAXED, __HIP_MEMORY_SCOPE_AGENT);
        while (__hip_atomic_load(bar, __ATOMIC_RELAXED, __HIP_MEMORY_SCOPE_AGENT) < target) {}
      }
      __syncthreads();
    }
  }
}

// ---------------------------------------------------------------- in-place LayerNorm
__global__ __launch_bounds__(256) void k_ln(float* __restrict__ out,
                                            const float* __restrict__ sr,
                                            const float* __restrict__ brr,
                                            const float* __restrict__ si,
                                            const float* __restrict__ bii) {
  int row = blockIdx.x * 4 + (threadIdx.x >> 6);   // 0..32767
  int lane = threadIdx.x & 63;
  float* p = out + (size_t)row * 512;
  float4 v1 = ((const float4*)p)[lane];
  float4 v2 = ((const float4*)p)[64 + lane];
  float s1 = v1.x + v1.y + v1.z + v1.w + v2.x + v2.y + v2.z + v2.w;
  float s2 = v1.x * v1.x + v1.y * v1.y + v1.z * v1.z + v1.w * v1.w +
             v2.x * v2.x + v2.y * v2.y + v2.z * v2.z + v2.w * v2.w;
#pragma unroll
  for (int m = 1; m < 64; m <<= 1) { s1 += __shfl_xor(s1, m, 64); s2 += __shfl_xor(s2, m, 64); }
  float mean = s1 * (1.f / 512.f);
  float var = s2 * (1.f / 512.f) - mean * mean;
  float inv = rsqrtf(var + 1e-6f);
  bool hi2 = row >= 16384;
  const float* sc = hi2 ? si : sr;
  const float* bs = hi2 ? bii : brr;
  float4 g1 = ((const float4*)sc)[lane], g2 = ((const float4*)sc)[64 + lane];
  float4 b1 = ((const float4*)bs)[lane], b2 = ((const float4*)bs)[64 + lane];
  v1.x = (v1.x - mean) * inv * g1.x + b1.x;
  v1.y = (v1.y - mean) * inv * g1.y + b1.y;
  v1.z = (v1.z - mean) * inv * g1.z + b1.z;
  v1.w = (v1.w - mean) * inv * g1.w + b1.w;
  v2.x = (v2.x - mean) * inv * g2.x + b2.x;
  v2.y = (v2.y - mean) * inv * g2.y + b2.y;
  v2.z = (v2.z - mean) * inv * g2.z + b2.z;
  v2.w = (v2.w - mean) * inv * g2.w + b2.w;
  ((float4*)p)[lane] = v1;
  ((float4*)p)[64 + lane] = v2;
}

// ---------------------------------------------------------------- launch
extern "C" void kernel_launch(void* const* d_in, const int* in_sizes, int n_in,
                              void* d_out, int out_size, void* d_ws, size_t ws_size,
                              hipStream_t stream) {
  const int*   tok   = (const int*)d_in[0];
  const float* emb_r = (const float*)d_in[1];
  const float* emb_i = (const float*)d_in[2];
  const float* Wr    = (const float*)d_in[3];
  const float* br    = (const float*)d_in[4];
  const float* Wu    = (const float*)d_in[5];
  const float* bu    = (const float*)d_in[6];
  const float* Wc    = (const float*)d_in[7];
  const float* bc    = (const float*)d_in[8];
  const float* lnrs  = (const float*)d_in[9];
  const float* lnrb  = (const float*)d_in[10];
  const float* lnis  = (const float*)d_in[11];
  const float* lnib  = (const float*)d_in[12];
  float* out = (float*)d_out;
  char* ws = (char*)d_ws;

  u16*   XS    = (u16*)(ws);                       //  33,554,432 B
  u16*   WT    = (u16*)(ws + 33554432);            //   6,291,456 B
  u16*   XW    = (u16*)(ws + 39845888);            // 100,663,296 B
  float* WhT   = (float*)(ws + 140509184);         //  12,582,912 B
  float* hbuf  = (float*)(ws + 153092096);         //      65,536 B
  float* rhbuf = (float*)(ws + 153157632);         //      32,768 B
  u32*   cnts  = (u32*)(ws + 153190400);           //       4,096 B

  k_init<<<1, 256, 0, stream>>>(hbuf, cnts);
  k_prep<<<6144, 256, 0, stream>>>(Wr, Wu, Wc, WT, WhT);
  k_gather<<<8192, 256, 0, stream>>>(tok, emb_r, emb_i, XS);
  k_gemm<<<3072, 256, 0, stream>>>(XS, WT, XW);
  k_gru<<<256, 256, 0, stream>>>(WhT, br, bu, bc, XW, hbuf, rhbuf, cnts, out);
  k_ln<<<8192, 256, 0, stream>>>(out, lnrs, lnrb, lnis, lnib);
}

// Round 3
// 18201.683 us; speedup vs baseline: 4.9398x; 1.3485x over previous
//
#include <hip/hip_runtime.h>
#include <hip/hip_bf16.h>

#define B_   8
#define T_   2048
#define D_   1024
#define OUT1_OFF 8388608ull   // 8*2048*512

typedef unsigned short u16;
typedef unsigned int   u32;
typedef unsigned long long u64;

__device__ __forceinline__ u16 f2bf(float f) {
  u32 u = __builtin_bit_cast(u32, f);
  u32 r = (u + 0x7fffu + ((u >> 16) & 1u)) >> 16;   // RNE
  return (u16)r;
}
__device__ __forceinline__ float bf2f(u16 s) {
  u32 u = ((u32)s) << 16;
  return __builtin_bit_cast(float, u);
}

// device-coherent (sc0 sc1, memory-side) data exchange helpers
__device__ __forceinline__ float4 ld4cv(const float* p) {
  u64 a = __hip_atomic_load((const u64*)p,     __ATOMIC_RELAXED, __HIP_MEMORY_SCOPE_AGENT);
  u64 b = __hip_atomic_load((const u64*)p + 1, __ATOMIC_RELAXED, __HIP_MEMORY_SCOPE_AGENT);
  float4 v;
  v.x = __builtin_bit_cast(float, (u32)a); v.y = __builtin_bit_cast(float, (u32)(a >> 32));
  v.z = __builtin_bit_cast(float, (u32)b); v.w = __builtin_bit_cast(float, (u32)(b >> 32));
  return v;
}
__device__ __forceinline__ float ld1cv(const float* p) {
  u32 a = __hip_atomic_load((const u32*)p, __ATOMIC_RELAXED, __HIP_MEMORY_SCOPE_AGENT);
  return __builtin_bit_cast(float, a);
}
__device__ __forceinline__ void st1cv(float* p, float v) {
  __hip_atomic_store((u32*)p, __builtin_bit_cast(u32, v), __ATOMIC_RELAXED, __HIP_MEMORY_SCOPE_AGENT);
}

// ---------------------------------------------------------------- init
__global__ void k_init(float* hbuf, u32* cnts) {
  int tid = threadIdx.x;
  for (int i = tid; i < 16384; i += 256) hbuf[i] = 0.f;   // both h parity buffers
  for (int i = tid; i < 2048; i += 256) cnts[i] = 0u;
}

// ---------------------------------------------------------------- weight prep
__global__ __launch_bounds__(256) void k_prep(const float* __restrict__ Wr,
                                              const float* __restrict__ Wu,
                                              const float* __restrict__ Wc,
                                              u16* __restrict__ WT,
                                              float* __restrict__ WhT) {
  __shared__ float tile[32][33];
  int bid = blockIdx.x;
  int g = bid >> 11;          // 0..2
  int rest = bid & 2047;
  int kt = rest >> 5;         // 0..63  (row tile over 2048)
  int jt = rest & 31;         // 0..31  (col tile over 1024)
  const float* W = (g == 0) ? Wr : ((g == 1) ? Wu : Wc);
  int tid = threadIdx.x;
  int r = tid >> 3, c4 = (tid & 7) * 4;
  const float4 v = *(const float4*)&W[(size_t)(kt * 32 + r) * 1024 + jt * 32 + c4];
  tile[r][c4 + 0] = v.x; tile[r][c4 + 1] = v.y;
  tile[r][c4 + 2] = v.z; tile[r][c4 + 3] = v.w;
  __syncthreads();
  int n = g * 1024 + jt * 32 + r;
  if (kt < 32) {
    int k = kt * 32 + c4;
    ushort4 o;
    o.x = f2bf(tile[c4 + 0][r]); o.y = f2bf(tile[c4 + 1][r]);
    o.z = f2bf(tile[c4 + 2][r]); o.w = f2bf(tile[c4 + 3][r]);
    *(ushort4*)&WT[(size_t)n * 1024 + k] = o;
  } else {
    int k = (kt - 32) * 32 + c4;
    float4 o;
    o.x = tile[c4 + 0][r]; o.y = tile[c4 + 1][r];
    o.z = tile[c4 + 2][r]; o.w = tile[c4 + 3][r];
    *(float4*)&WhT[(size_t)n * 1024 + k] = o;
  }
}

// ---------------------------------------------------------------- embedding gather -> bf16
__global__ __launch_bounds__(256) void k_gather(const int* __restrict__ tok,
                                                const float* __restrict__ er,
                                                const float* __restrict__ ei,
                                                u16* __restrict__ XS) {
  int row = blockIdx.x * 2 + (threadIdx.x >> 7);  // 0..16383 = b*T+t
  int lt = threadIdx.x & 127;
  int tk = tok[row];
  int c0 = lt * 8;
  const float* p = (c0 < 512) ? (er + (size_t)tk * 512 + c0)
                              : (ei + (size_t)tk * 512 + (c0 - 512));
  float4 v1 = *(const float4*)p;
  float4 v2 = *(const float4*)(p + 4);
  uint4 o;
  o.x = (u32)f2bf(v1.x) | ((u32)f2bf(v1.y) << 16);
  o.y = (u32)f2bf(v1.z) | ((u32)f2bf(v1.w) << 16);
  o.z = (u32)f2bf(v2.x) | ((u32)f2bf(v2.y) << 16);
  o.w = (u32)f2bf(v2.z) | ((u32)f2bf(v2.w) << 16);
  *(uint4*)&XS[(size_t)row * 1024 + c0] = o;
}

// ---------------------------------------------------------------- bf16 MFMA GEMM: XW = XS @ W_top
typedef __attribute__((ext_vector_type(8))) __bf16 bf16x8;
typedef __attribute__((ext_vector_type(4))) float f32x4;

__device__ __forceinline__ void gload16(const void* g, void* l) {
  __builtin_amdgcn_global_load_lds((const __attribute__((address_space(1))) void*)g,
                                   (__attribute__((address_space(3))) void*)l, 16, 0, 0);
}

__global__ __launch_bounds__(256) void k_gemm(const u16* __restrict__ XS,
                                              const u16* __restrict__ WT,
                                              u16* __restrict__ XW) {
  __shared__ u16 As[128 * 32];
  __shared__ u16 Bs[128 * 32];
  int bid = blockIdx.x;
  int m0 = (bid & 127) * 128;   // 128 m-tiles
  int n0 = (bid >> 7) * 128;    // 24 n-tiles
  int tid = threadIdx.x;
  int wave = tid >> 6, lane = tid & 63;
  int wm = wave >> 1, wn = wave & 1;
  f32x4 acc[4][4] = {};
  int lr = lane & 15, lk = (lane >> 4) * 8;
  int srow = lane >> 2, sc8 = (lane & 3) * 8;
  for (int k0 = 0; k0 < 1024; k0 += 32) {
#pragma unroll
    for (int q = 0; q < 2; ++q) {
      int rbase = wave * 32 + q * 16;
      gload16(XS + (size_t)(m0 + rbase + srow) * 1024 + k0 + sc8, &As[rbase * 32]);
      gload16(WT + (size_t)(n0 + rbase + srow) * 1024 + k0 + sc8, &Bs[rbase * 32]);
    }
    __syncthreads();
    bf16x8 a[4], b[4];
#pragma unroll
    for (int mi = 0; mi < 4; ++mi) a[mi] = *(const bf16x8*)&As[(wm * 64 + mi * 16 + lr) * 32 + lk];
#pragma unroll
    for (int ni = 0; ni < 4; ++ni) b[ni] = *(const bf16x8*)&Bs[(wn * 64 + ni * 16 + lr) * 32 + lk];
#pragma unroll
    for (int mi = 0; mi < 4; ++mi)
#pragma unroll
      for (int ni = 0; ni < 4; ++ni)
        acc[mi][ni] = __builtin_amdgcn_mfma_f32_16x16x32_bf16(a[mi], b[ni], acc[mi][ni], 0, 0, 0);
    __syncthreads();
  }
#pragma unroll
  for (int mi = 0; mi < 4; ++mi)
#pragma unroll
    for (int ni = 0; ni < 4; ++ni) {
      int col = n0 + wn * 64 + ni * 16 + lr;
#pragma unroll
      for (int r = 0; r < 4; ++r) {
        int row = m0 + wm * 64 + mi * 16 + (lane >> 4) * 4 + r;
        XW[(size_t)row * 3072 + col] = f2bf(acc[mi][ni][r]);
      }
    }
}

// ---------------------------------------------------------------- persistent GRU
#define WPAD 1028

__device__ __forceinline__ float butterfly_reduce(float (&p)[64], int lane) {
#pragma unroll
  for (int s = 0; s < 6; ++s) {
    const int m = 1 << s;
    const int bit = (lane >> s) & 1;
#pragma unroll
    for (int i = 0; i < (64 >> (s + 1)); ++i) {
      float lo = p[2 * i], hi = p[2 * i + 1];
      float mine = bit ? hi : lo;
      float send = bit ? lo : hi;
      float recv = __shfl_xor(send, m, 64);
      p[i] = mine + recv;
    }
  }
  return p[0];
}

__global__ __launch_bounds__(256, 1) void k_gru(const float* __restrict__ WhT,
                                                const float* __restrict__ br,
                                                const float* __restrict__ bu,
                                                const float* __restrict__ bc,
                                                const u16* __restrict__ XW,
                                                float* hbuf, float* rhbuf,
                                                u32* cnts, float* out) {
  __shared__ float Wl[12][WPAD];   // rows 0-3: Wr cols, 4-7: Wu, 8-11: Wc
  __shared__ float part[4][64];
  __shared__ float u_l[4][8];
  __shared__ float hold[4][8];

  const int tid = threadIdx.x;
  const int lane = tid & 63;
  const int wave = tid >> 6;
  const int j0 = blockIdx.x * 4;
  const int slot = blockIdx.x & 7;
  const int k4 = tid * 4;
  // two-level barrier lines (256B apart): slotA s*64, relA 512, slotB 576+s*64, relB 1088
  u32* slotA = cnts + slot * 64;
  u32* relA  = cnts + 512;
  u32* slotB = cnts + 576 + slot * 64;
  u32* relB  = cnts + 1088;

  for (int i = tid; i < 12 * 1024; i += 256) {
    int c = i >> 10, k = i & 1023;
    int g = c >> 2, jj = c & 3;
    Wl[c][k] = WhT[(size_t)(g * 1024 + j0 + jj) * 1024 + k];
  }

  float biasA = 0.f;
  if (tid < 64) {
    int wA = tid >> 3, gA = wA >> 2, jjA = wA & 3;
    biasA = (gA == 0) ? br[j0 + jjA] : bu[j0 + jjA];
  }
  float bcB = 0.f;
  if (tid < 32) bcB = bc[j0 + (tid >> 3)];

  __syncthreads();

  for (int t = 0; t < T_; ++t) {
    const float* hprev = hbuf + ((t + 1) & 1) * 8192;

    // prefetch finalize-A operands (overlaps with MAC)
    float xwA = 0.f, hjA = 0.f;
    if (tid < 64) {
      int bA = tid & 7, wA = tid >> 3, gA = wA >> 2, jjA = wA & 3;
      xwA = bf2f(XW[((size_t)bA * T_ + t) * 3072 + gA * 1024 + (j0 + jjA)]);
      hjA = ld1cv(&hprev[bA * 1024 + j0 + jjA]);
    }

    // ---- phase A: r,u pre-activations (register-blocked 8x8 over 4-k chunk)
    float4 hv[8], wv[8];
#pragma unroll
    for (int b = 0; b < 8; ++b) hv[b] = ld4cv(&hprev[b * 1024 + k4]);
#pragma unroll
    for (int w = 0; w < 8; ++w) wv[w] = *(const float4*)&Wl[w][k4];
    float acc[64];
#pragma unroll
    for (int w = 0; w < 8; ++w)
#pragma unroll
      for (int b = 0; b < 8; ++b)
        acc[w * 8 + b] = hv[b].x * wv[w].x + hv[b].y * wv[w].y +
                         hv[b].z * wv[w].z + hv[b].w * wv[w].w;
    float pa = butterfly_reduce(acc, lane);
    part[wave][lane] = pa;
    __syncthreads();

    if (tid < 64) {
      float dot = part[0][tid] + part[1][tid] + part[2][tid] + part[3][tid];
      float pre = dot + xwA + biasA;
      float sg = 1.f / (1.f + __expf(-pre));
      int bA = tid & 7, wA = tid >> 3, gA = wA >> 2, jjA = wA & 3;
      if (gA == 0) {
        st1cv(&rhbuf[bA * 1024 + j0 + jjA], sg * hjA);
      } else {
        u_l[jjA][bA] = sg;
        hold[jjA][bA] = hjA;
      }
    }
    __syncthreads();   // implicit vmcnt(0): rh write-through complete for all waves
    if (tid == 0) {
      u32 prev = __hip_atomic_fetch_add(slotA, 1u, __ATOMIC_RELAXED, __HIP_MEMORY_SCOPE_AGENT);
      if (prev + 1 == 32u * (u32)(t + 1))
        __hip_atomic_fetch_add(relA, 1u, __ATOMIC_RELAXED, __HIP_MEMORY_SCOPE_AGENT);
      while (__hip_atomic_load(relA, __ATOMIC_RELAXED, __HIP_MEMORY_SCOPE_AGENT) < 8u * (u32)(t + 1)) {}
    }
    __syncthreads();

    // ---- phase B: c, h_new
    float xwB = 0.f;
    if (tid < 32) {
      xwB = bf2f(XW[((size_t)(tid & 7) * T_ + t) * 3072 + 2048 + j0 + (tid >> 3)]);
    }
    float4 rv[8], wc4[4];
#pragma unroll
    for (int b = 0; b < 8; ++b) rv[b] = ld4cv(&rhbuf[b * 1024 + k4]);
#pragma unroll
    for (int c = 0; c < 4; ++c) wc4[c] = *(const float4*)&Wl[8 + c][k4];
#pragma unroll
    for (int w = 0; w < 8; ++w)
#pragma unroll
      for (int b = 0; b < 8; ++b) {
        float4 w2 = wc4[w & 3];
        acc[w * 8 + b] = rv[b].x * w2.x + rv[b].y * w2.y +
                         rv[b].z * w2.z + rv[b].w * w2.w;
      }
    float pb = butterfly_reduce(acc, lane);
    part[wave][lane] = pb;
    __syncthreads();
    if (tid < 32) {
      float dot = part[0][tid] + part[1][tid] + part[2][tid] + part[3][tid];
      float pre = dot + xwB + bcB;
      float ax = fabsf(pre);
      float e = __expf(-2.f * ax);
      float cv = copysignf((1.f - e) / (1.f + e), pre);
      int bB = tid & 7, jjB = tid >> 3;
      float uu = u_l[jjB][bB];
      float hn = (1.f - uu) * hold[jjB][bB] + uu * cv;
      int j = j0 + jjB;
      st1cv(&hbuf[(t & 1) * 8192 + bB * 1024 + j], hn);
      size_t orow = (size_t)bB * T_ + t;
      if (j < 512) out[orow * 512 + j] = hn;
      else out[OUT1_OFF + orow * 512 + (j - 512)] = hn;
    }
    __syncthreads();   // implicit vmcnt(0): h write-through complete for all waves
    if (t < T_ - 1) {
      if (tid == 0) {
        u32 prev = __hip_atomic_fetch_add(slotB, 1u, __ATOMIC_RELAXED, __HIP_MEMORY_SCOPE_AGENT);
        if (prev + 1 == 32u * (u32)(t + 1))
          __hip_atomic_fetch_add(relB, 1u, __ATOMIC_RELAXED, __HIP_MEMORY_SCOPE_AGENT);
        while (__hip_atomic_load(relB, __ATOMIC_RELAXED, __HIP_MEMORY_SCOPE_AGENT) < 8u * (u32)(t + 1)) {}
      }
      __syncthreads();
    }
  }
}

// ---------------------------------------------------------------- in-place LayerNorm
__global__ __launch_bounds__(256) void k_ln(float* __restrict__ out,
                                            const float* __restrict__ sr,
                                            const float* __restrict__ brr,
                                            const float* __restrict__ si,
                                            const float* __restrict__ bii) {
  int row = blockIdx.x * 4 + (threadIdx.x >> 6);   // 0..32767
  int lane = threadIdx.x & 63;
  float* p = out + (size_t)row * 512;
  float4 v1 = ((const float4*)p)[lane];
  float4 v2 = ((const float4*)p)[64 + lane];
  float s1 = v1.x + v1.y + v1.z + v1.w + v2.x + v2.y + v2.z + v2.w;
  float s2 = v1.x * v1.x + v1.y * v1.y + v1.z * v1.z + v1.w * v1.w +
             v2.x * v2.x + v2.y * v2.y + v2.z * v2.z + v2.w * v2.w;
#pragma unroll
  for (int m = 1; m < 64; m <<= 1) { s1 += __shfl_xor(s1, m, 64); s2 += __shfl_xor(s2, m, 64); }
  float mean = s1 * (1.f / 512.f);
  float var = s2 * (1.f / 512.f) - mean * mean;
  float inv = rsqrtf(var + 1e-6f);
  bool hi2 = row >= 16384;
  const float* sc = hi2 ? si : sr;
  const float* bs = hi2 ? bii : brr;
  float4 g1 = ((const float4*)sc)[lane], g2 = ((const float4*)sc)[64 + lane];
  float4 b1 = ((const float4*)bs)[lane], b2 = ((const float4*)bs)[64 + lane];
  v1.x = (v1.x - mean) * inv * g1.x + b1.x;
  v1.y = (v1.y - mean) * inv * g1.y + b1.y;
  v1.z = (v1.z - mean) * inv * g1.z + b1.z;
  v1.w = (v1.w - mean) * inv * g1.w + b1.w;
  v2.x = (v2.x - mean) * inv * g2.x + b2.x;
  v2.y = (v2.y - mean) * inv * g2.y + b2.y;
  v2.z = (v2.z - mean) * inv * g2.z + b2.z;
  v2.w = (v2.w - mean) * inv * g2.w + b2.w;
  ((float4*)p)[lane] = v1;
  ((float4*)p)[64 + lane] = v2;
}

// ---------------------------------------------------------------- launch
extern "C" void kernel_launch(void* const* d_in, const int* in_sizes, int n_in,
                              void* d_out, int out_size, void* d_ws, size_t ws_size,
                              hipStream_t stream) {
  const int*   tok   = (const int*)d_in[0];
  const float* emb_r = (const float*)d_in[1];
  const float* emb_i = (const float*)d_in[2];
  const float* Wr    = (const float*)d_in[3];
  const float* br    = (const float*)d_in[4];
  const float* Wu    = (const float*)d_in[5];
  const float* bu    = (const float*)d_in[6];
  const float* Wc    = (const float*)d_in[7];
  const float* bc    = (const float*)d_in[8];
  const float* lnrs  = (const float*)d_in[9];
  const float* lnrb  = (const float*)d_in[10];
  const float* lnis  = (const float*)d_in[11];
  const float* lnib  = (const float*)d_in[12];
  float* out = (float*)d_out;
  char* ws = (char*)d_ws;

  u16*   XS    = (u16*)(ws);                       //  33,554,432 B
  u16*   WT    = (u16*)(ws + 33554432);            //   6,291,456 B
  u16*   XW    = (u16*)(ws + 39845888);            // 100,663,296 B
  float* WhT   = (float*)(ws + 140509184);         //  12,582,912 B
  float* hbuf  = (float*)(ws + 153092096);         //      65,536 B
  float* rhbuf = (float*)(ws + 153157632);         //      32,768 B
  u32*   cnts  = (u32*)(ws + 153190400);           //       8,192 B

  k_init<<<1, 256, 0, stream>>>(hbuf, cnts);
  k_prep<<<6144, 256, 0, stream>>>(Wr, Wu, Wc, WT, WhT);
  k_gather<<<8192, 256, 0, stream>>>(tok, emb_r, emb_i, XS);
  k_gemm<<<3072, 256, 0, stream>>>(XS, WT, XW);
  k_gru<<<256, 256, 0, stream>>>(WhT, br, bu, bc, XW, hbuf, rhbuf, cnts, out);
  k_ln<<<8192, 256, 0, stream>>>(out, lnrs, lnrb, lnis, lnib);
}